// Round 23
// baseline (104.874 us; speedup 1.0000x reference)
//
#include <hip/hip_runtime.h>
#include <hip/hip_bf16.h>
#include <math.h>

#define NB 4096   // batch
#define ND 2048   // feature dim
#define BT 128    // output tile (128x128)
#define NTB (NB / BT)            // 32 tile-blocks per dim
#define NBLK (NTB * (NTB + 1) / 2)  // 528 upper-tri blocks (= 8*66)
#define NKT (ND / 128)           // 16 K-tiles of 128
#define TPC 68                   // padded pack row (ushorts)

typedef __attribute__((ext_vector_type(8))) short short8;
typedef __attribute__((ext_vector_type(4))) float floatx4;
typedef __attribute__((ext_vector_type(4))) unsigned short ushort4v;

#define GLOAD_LDS16(g, l) \
  __builtin_amdgcn_global_load_lds((const __attribute__((address_space(1))) void*)(g), \
                                   (__attribute__((address_space(3))) void*)(l), 16, 0, 0)

__device__ __forceinline__ unsigned f2bf(float x) {  // RNE fp32 -> bf16 bits
  unsigned u = __float_as_uint(x);
  return (u + 0x7FFFu + ((u >> 16) & 1u)) >> 16;
}

union H16 { unsigned short u; _Float16 h; };
__device__ __forceinline__ unsigned short f2h(float x) { H16 c; c.h = (_Float16)x; return c.u; }
__device__ __forceinline__ float h2f(unsigned short u) { H16 c; c.u = u; return (float)c.h; }

// ---- kernel 1: L2-normalize rows -> bf16 ----
__global__ __launch_bounds__(256) void norm_kernel(const float* __restrict__ feats,
                                                   unsigned short* __restrict__ fb) {
  int row = blockIdx.x;
  int t = threadIdx.x;
  const float4* src = (const float4*)(feats + (size_t)row * ND);
  float4 v0 = src[t * 2];
  float4 v1 = src[t * 2 + 1];
  float ss = v0.x * v0.x + v0.y * v0.y + v0.z * v0.z + v0.w * v0.w +
             v1.x * v1.x + v1.y * v1.y + v1.z * v1.z + v1.w * v1.w;
  for (int off = 32; off > 0; off >>= 1) ss += __shfl_down(ss, off);
  __shared__ float wsum[4];
  int lane = t & 63, wid = t >> 6;
  if (lane == 0) wsum[wid] = ss;
  __syncthreads();
  float tot = wsum[0] + wsum[1] + wsum[2] + wsum[3];
  float inv = 1.0f / (sqrtf(tot) + 1e-12f);
  uint4 o;
  o.x = f2bf(v0.x * inv) | (f2bf(v0.y * inv) << 16);
  o.y = f2bf(v0.z * inv) | (f2bf(v0.w * inv) << 16);
  o.z = f2bf(v1.x * inv) | (f2bf(v1.y * inv) << 16);
  o.w = f2bf(v1.z * inv) | (f2bf(v1.w * inv) << 16);
  ((uint4*)(fb + (size_t)row * ND))[t] = o;
}

// ---- kernel 2: triangular 128x128 tile, 8 waves, BK=128, 2-buf (16 sync units) ----
__global__ __launch_bounds__(512) void pass0_kernel(const unsigned short* __restrict__ fb,
                                                    unsigned short* __restrict__ sim) {
  // 2 x (A 32KB + B 32KB) = 128KB; epilogue packs (17.4KB) reuse the region
  __shared__ __align__(16) char shraw[131072];

  int tid = threadIdx.x;
  int l = tid & 63, wv = tid >> 6;
  int wm = wv >> 2, wn = wv & 3;   // 2 x 4 wave grid: each wave 64 rows x 32 cols

  // XCD swizzle (bijective: 528 = 8 * 66) + triangle decode
  int bid = (blockIdx.x & 7) * 66 + (blockIdx.x >> 3);
  int rem = bid, bi = 0;
  while (rem >= NTB - bi) { rem -= NTB - bi; bi++; }
  int bj = bi + rem;
  int row0 = bi * BT, col0 = bj * BT;

  // stage K-tile ts into buffer q (4+4 gloads/thread): linear LDS dest,
  // LDS slot c_ holds global chunk c_ ^ (r_&7)  [same involution family as R14;
  // c_ in 0..15, XOR flips low 3 bits only -> stays in-row, bijective]
  auto stageT = [&](int q, int ts) {
    char* SA = shraw + q * 65536;
    char* SB = SA + 32768;
#pragma unroll
    for (int e = 0; e < 4; e++) {
      int li = e * 512 + tid;          // 0..2047
      int r_ = li >> 4, c_ = li & 15;
      int gk = ts * 128 + ((c_ ^ (r_ & 7)) * 8);
      GLOAD_LDS16(fb + (size_t)(row0 + r_) * ND + gk, SA + li * 16);
      GLOAD_LDS16(fb + (size_t)(col0 + r_) * ND + gk, SB + li * 16);
    }
  };

  floatx4 acc[4][2];
#pragma unroll
  for (int j = 0; j < 4; j++)
#pragma unroll
    for (int r = 0; r < 2; r++) acc[j][r] = (floatx4){0.f, 0.f, 0.f, 0.f};

  // fragment offsets: row stride 256B (16 chunks); slot = ck ^ (row&7)
  int offA[4][4], offB[2][4];
#pragma unroll
  for (int j = 0; j < 4; j++) {
    int rh = wm * 64 + j * 16 + (l & 15);
#pragma unroll
    for (int s = 0; s < 4; s++) {
      int ck = s * 4 + (l >> 4);
      offA[j][s] = rh * 256 + ((ck ^ (rh & 7)) * 16);
    }
  }
#pragma unroll
  for (int r = 0; r < 2; r++) {
    int rh = wn * 32 + r * 16 + (l & 15);
#pragma unroll
    for (int s = 0; s < 4; s++) {
      int ck = s * 4 + (l >> 4);
      offB[r][s] = rh * 256 + ((ck ^ (rh & 7)) * 16);
    }
  }

  // prologue: tile0 resident
  stageT(0, 0);
  __syncthreads();

  // per tile: stage(u+1) -> 24 ds_reads -> [compiler lgkm] -> 32 MFMA -> sync
  for (int u = 0; u < NKT; u++) {
    const char* AP = shraw + (u & 1) * 65536;
    const char* BP = AP + 32768;
    if (u + 1 < NKT) stageT((u + 1) & 1, u + 1);   // overlap with reads+MFMA
    short8 a_[4][4], b_[2][4];
#pragma unroll
    for (int j = 0; j < 4; j++)
#pragma unroll
      for (int s = 0; s < 4; s++)
        a_[j][s] = *(const short8*)(AP + offA[j][s]);
#pragma unroll
    for (int r = 0; r < 2; r++)
#pragma unroll
      for (int s = 0; s < 4; s++)
        b_[r][s] = *(const short8*)(BP + offB[r][s]);
#pragma unroll
    for (int j = 0; j < 4; j++)
#pragma unroll
      for (int r = 0; r < 2; r++)
#pragma unroll
        for (int s = 0; s < 4; s++)
          acc[j][r] = __builtin_amdgcn_mfma_f32_16x16x32_bf16(a_[j][s], b_[r][s], acc[j][r], 0, 0, 0);
    __syncthreads();   // drains vmcnt/lgkm: stage(u+1) resident, reads of u done
  }

  // element (row_l, col_l): row_l = wm*64 + j*16 + (l>>4)*4 + v,
  //                         col_l = wn*32 + r*16 + (l&15)

  // ---- C^T pack + store -> mirror block [col0, row0] (covers diagonal too) ----
#pragma unroll
  for (int h = 0; h < 2; h++) {
    __syncthreads();
    unsigned short (*tileT)[TPC] = (unsigned short(*)[TPC])shraw;
    if (wm == h) {
#pragma unroll
      for (int j = 0; j < 4; j++) {
        int lr = j * 16 + (l >> 4) * 4;   // local orig-row within chunk (0..63)
#pragma unroll
        for (int r = 0; r < 2; r++) {
          int C = wn * 32 + r * 16 + (l & 15);
          ushort4v pk;
          pk[0] = f2h(acc[j][r][0]);
          pk[1] = f2h(acc[j][r][1]);
          pk[2] = f2h(acc[j][r][2]);
          pk[3] = f2h(acc[j][r][3]);
          *(ushort4v*)(&tileT[C][lr]) = pk;
        }
      }
    }
    __syncthreads();
    int c = tid >> 2, seg = tid & 3;     // 128 rows x 4 threads, 16 elems each
    const unsigned short* srcp = &tileT[c][seg * 16];
    unsigned short* dstp = sim + (size_t)(col0 + c) * NB + row0 + h * 64 + seg * 16;
    *(short8*)(dstp) = *(const short8*)(srcp);
    *(short8*)(dstp + 8) = *(const short8*)(srcp + 8);
  }

  // ---- direct pack + store -> own block [row0, col0] (off-diagonal only) ----
  if (bi != bj) {
#pragma unroll
    for (int h = 0; h < 2; h++) {
      __syncthreads();
      unsigned short (*tileR)[TPC] = (unsigned short(*)[TPC])shraw;
      if ((wn >> 1) == h) {
#pragma unroll
        for (int j = 0; j < 4; j++)
#pragma unroll
          for (int r = 0; r < 2; r++) {
            int row_l = wm * 64 + j * 16 + (l >> 4) * 4;
            int ch = (wn & 1) * 32 + r * 16 + (l & 15);   // col within chunk
#pragma unroll
            for (int v = 0; v < 4; v++)
              tileR[row_l + v][ch] = f2h(acc[j][r][v]);
          }
      }
      __syncthreads();
      int r_ = tid >> 2, seg = tid & 3;
      const unsigned short* srcp = &tileR[r_][seg * 16];
      unsigned short* dstp = sim + (size_t)(row0 + r_) * NB + col0 + h * 64 + seg * 16;
      *(short8*)(dstp) = *(const short8*)(srcp);
      *(short8*)(dstp + 8) = *(const short8*)(srcp + 8);
    }
  }
}

// ---- kernel 3: fused stats + exp-sums, FOUR waves per row (quarter-row each) ----
__global__ __launch_bounds__(512) void sums_kernel(const unsigned short* __restrict__ sim,
                                                   const int* __restrict__ labels,
                                                   float* __restrict__ gps,
                                                   float* __restrict__ gns) {
  int t = threadIdx.x, l = t & 63, w = t >> 6;   // 8 waves
  int rloc = w >> 2, quarter = w & 3;            // 2 rows/block, 4 waves/row
  int r = blockIdx.x * 2 + rloc;
  int rl = labels[r];
  const unsigned short* row = sim + (size_t)r * NB + quarter * 1024;
  int jbase = quarter * 1024;

  short8 sv[2];
  float pmin = 3.0e38f, nmax = -3.0e38f;
#pragma unroll
  for (int it = 0; it < 2; it++) {
    int j0 = it * 512 + l * 8;
    sv[it] = *(const short8*)(row + j0);
    int4 lb0 = *(const int4*)(labels + jbase + j0);
    int4 lb1 = *(const int4*)(labels + jbase + j0 + 4);
    int lb[8] = {lb0.x, lb0.y, lb0.z, lb0.w, lb1.x, lb1.y, lb1.z, lb1.w};
#pragma unroll
    for (int e = 0; e < 8; e++) {
      float s = h2f((unsigned short)sv[it][e]);
      int j = jbase + j0 + e;
      if (lb[e] == rl) {
        if (j != r && s < 0.99999f) pmin = fminf(pmin, s);
      } else {
        nmax = fmaxf(nmax, s);
      }
    }
  }
#pragma unroll
  for (int off = 1; off < 64; off <<= 1) {
    pmin = fminf(pmin, __shfl_xor(pmin, off));
    nmax = fmaxf(nmax, __shfl_xor(nmax, off));
  }
  // combine the 4 quarter-row waves
  __shared__ float spm[8], snm[8], sps[8], sns[8];
  if (l == 0) { spm[w] = pmin; snm[w] = nmax; }
  __syncthreads();
  int g = w & ~3;
  pmin = fminf(fminf(spm[g], spm[g + 1]), fminf(spm[g + 2], spm[g + 3]));
  nmax = fmaxf(fmaxf(snm[g], snm[g + 1]), fmaxf(snm[g + 2], snm[g + 3]));
  // empty-mask semantics: sentinels keep masks false -> sums 0 -> invalid (matches ref)

  float ps0 = 0.f, ps1 = 0.f, ns0 = 0.f, ns1 = 0.f;
#pragma unroll
  for (int it = 0; it < 2; it++) {
    int j0 = it * 512 + l * 8;
    int4 lb0 = *(const int4*)(labels + jbase + j0);
    int4 lb1 = *(const int4*)(labels + jbase + j0 + 4);
    int lb[8] = {lb0.x, lb0.y, lb0.z, lb0.w, lb1.x, lb1.y, lb1.z, lb1.w};
#pragma unroll
    for (int e = 0; e < 8; e++) {
      float s = h2f((unsigned short)sv[it][e]);
      int j = jbase + j0 + e;
      float pv = 0.f, nv = 0.f;
      if (lb[e] == rl) {
        if (j != r && s < 0.99999f && (s - 0.1f < nmax)) pv = __expf(-2.0f * (s - 0.5f));
      } else {
        if (s + 0.1f > pmin) nv = __expf(40.0f * (s - 0.5f));
      }
      if (e & 1) { ps1 += pv; ns1 += nv; }
      else       { ps0 += pv; ns0 += nv; }
    }
  }
  float ps = ps0 + ps1, ns = ns0 + ns1;
  for (int off = 32; off > 0; off >>= 1) {
    ps += __shfl_down(ps, off);
    ns += __shfl_down(ns, off);
  }
  if (l == 0) { sps[w] = ps; sns[w] = ns; }
  __syncthreads();
  if (t < 2) {
    gps[blockIdx.x * 2 + t] = sps[4 * t] + sps[4 * t + 1] + sps[4 * t + 2] + sps[4 * t + 3];
    gns[blockIdx.x * 2 + t] = sns[4 * t] + sns[4 * t + 1] + sns[4 * t + 2] + sns[4 * t + 3];
  }
}

// ---- kernel 4: finalize scalar loss ----
__global__ __launch_bounds__(256) void finalize_kernel(const float* __restrict__ gps,
                                                       const float* __restrict__ gns,
                                                       float* __restrict__ out) {
  int t = threadIdx.x;
  float sum = 0.f;
  for (int i = t; i < NB; i += 256) {
    float ps = gps[i], ns = gns[i];
    if (ps > 0.f && ns > 0.f) sum += 0.5f * log1pf(ps) + 0.025f * log1pf(ns);
  }
  for (int off = 32; off > 0; off >>= 1) sum += __shfl_down(sum, off);
  __shared__ float wsum[4];
  int lane = t & 63, wid = t >> 6;
  if (lane == 0) wsum[wid] = sum;
  __syncthreads();
  if (t == 0) out[0] = (wsum[0] + wsum[1] + wsum[2] + wsum[3]) / (float)NB;
}

extern "C" void kernel_launch(void* const* d_in, const int* in_sizes, int n_in,
                              void* d_out, int out_size, void* d_ws, size_t ws_size,
                              hipStream_t stream) {
  const float* feats = (const float*)d_in[0];
  const int* labels = (const int*)d_in[1];

  char* ws = (char*)d_ws;
  unsigned short* fb = (unsigned short*)ws;                  // 16 MB bf16 normalized feats
  size_t off = (size_t)NB * ND * 2;
  unsigned short* sim = (unsigned short*)(ws + off);         // 32 MB fp16 sim (full)
  off += (size_t)NB * NB * 2;
  float* gps = (float*)(ws + off); off += NB * 4;
  float* gns = (float*)(ws + off); off += NB * 4;

  norm_kernel<<<NB, 256, 0, stream>>>(feats, fb);
  pass0_kernel<<<NBLK, 512, 0, stream>>>(fb, sim);
  sums_kernel<<<NB / 2, 512, 0, stream>>>(sim, labels, gps, gns);
  finalize_kernel<<<1, 256, 0, stream>>>(gps, gns, (float*)d_out);
}

// Round 24
// 95.525 us; speedup vs baseline: 1.0979x; 1.0979x over previous
//
#include <hip/hip_runtime.h>
#include <hip/hip_bf16.h>
#include <math.h>

#define NB 4096   // batch
#define ND 2048   // feature dim
#define BT 128    // output tile (128x128)
#define NTB (NB / BT)            // 32 tile-blocks per dim
#define NBLK (NTB * (NTB + 1) / 2)  // 528 upper-tri blocks
#define NKT (ND / 64)            // 32 K-tiles of 64
#define TPC 68                   // padded pack row (ushorts)

typedef __attribute__((ext_vector_type(8))) short short8;
typedef __attribute__((ext_vector_type(4))) float floatx4;
typedef __attribute__((ext_vector_type(4))) unsigned short ushort4v;

#define GLOAD_LDS16(g, l) \
  __builtin_amdgcn_global_load_lds((const __attribute__((address_space(1))) void*)(g), \
                                   (__attribute__((address_space(3))) void*)(l), 16, 0, 0)

__device__ __forceinline__ unsigned f2bf(float x) {  // RNE fp32 -> bf16 bits
  unsigned u = __float_as_uint(x);
  return (u + 0x7FFFu + ((u >> 16) & 1u)) >> 16;
}

union H16 { unsigned short u; _Float16 h; };
__device__ __forceinline__ unsigned short f2h(float x) { H16 c; c.h = (_Float16)x; return c.u; }
__device__ __forceinline__ float h2f(unsigned short u) { H16 c; c.u = u; return (float)c.h; }

// ---- kernel 1: L2-normalize rows -> bf16 ----
__global__ __launch_bounds__(256) void norm_kernel(const float* __restrict__ feats,
                                                   unsigned short* __restrict__ fb) {
  int row = blockIdx.x;
  int t = threadIdx.x;
  const float4* src = (const float4*)(feats + (size_t)row * ND);
  float4 v0 = src[t * 2];
  float4 v1 = src[t * 2 + 1];
  float ss = v0.x * v0.x + v0.y * v0.y + v0.z * v0.z + v0.w * v0.w +
             v1.x * v1.x + v1.y * v1.y + v1.z * v1.z + v1.w * v1.w;
  for (int off = 32; off > 0; off >>= 1) ss += __shfl_down(ss, off);
  __shared__ float wsum[4];
  int lane = t & 63, wid = t >> 6;
  if (lane == 0) wsum[wid] = ss;
  __syncthreads();
  float tot = wsum[0] + wsum[1] + wsum[2] + wsum[3];
  float inv = 1.0f / (sqrtf(tot) + 1e-12f);
  uint4 o;
  o.x = f2bf(v0.x * inv) | (f2bf(v0.y * inv) << 16);
  o.y = f2bf(v0.z * inv) | (f2bf(v0.w * inv) << 16);
  o.z = f2bf(v1.x * inv) | (f2bf(v1.y * inv) << 16);
  o.w = f2bf(v1.z * inv) | (f2bf(v1.w * inv) << 16);
  ((uint4*)(fb + (size_t)row * ND))[t] = o;
}

// ---- kernel 2: triangular 128x128 tile, 8 waves, BK=64, 3-buf counted vmcnt ----
__global__ __launch_bounds__(512) void pass0_kernel(const unsigned short* __restrict__ fb,
                                                    unsigned short* __restrict__ sim) {
  // 3 x (A 16KB + B 16KB) = 96KB; epilogue packs (17.4KB) reuse the region
  __shared__ __align__(16) char shraw[98304];

  int tid = threadIdx.x;
  int l = tid & 63, wv = tid >> 6;
  int wm = wv >> 2, wn = wv & 3;   // 2 x 4 wave grid: each wave 64 rows x 32 cols

  // XCD swizzle (bijective: 528 = 8 * 66)
  int bid = (blockIdx.x & 7) * 66 + (blockIdx.x >> 3);
  int rem = bid, bi = 0;
  while (rem >= NTB - bi) { rem -= NTB - bi; bi++; }
  int bj = bi + rem;
  int row0 = bi * BT, col0 = bj * BT;

  // stage K-tile ts into buffer q (4 gloads/thread): linear LDS dest,
  // LDS slot c_ holds global chunk c_ ^ (r_&7)  [R14-verified]
  auto stageT = [&](int q, int ts) {
    char* SA = shraw + q * 32768;
    char* SB = SA + 16384;
#pragma unroll
    for (int e = 0; e < 2; e++) {
      int li = e * 512 + tid;          // 0..1023
      int r_ = li >> 3, c_ = li & 7;
      int gk = ts * 64 + ((c_ ^ (r_ & 7)) * 8);
      GLOAD_LDS16(fb + (size_t)(row0 + r_) * ND + gk, SA + li * 16);
      GLOAD_LDS16(fb + (size_t)(col0 + r_) * ND + gk, SB + li * 16);
    }
  };

  floatx4 acc[4][2];
#pragma unroll
  for (int j = 0; j < 4; j++)
#pragma unroll
    for (int r = 0; r < 2; r++) acc[j][r] = (floatx4){0.f, 0.f, 0.f, 0.f};

  // R14-verified fragment offsets: slot = (s*4 + (l>>4)) ^ (row&7)
  int offA[4][2], offB[2][2];
#pragma unroll
  for (int j = 0; j < 4; j++) {
    int rh = wm * 64 + j * 16 + (l & 15);
#pragma unroll
    for (int s = 0; s < 2; s++) {
      int ck = s * 4 + (l >> 4);
      offA[j][s] = rh * 128 + ((ck ^ (rh & 7)) * 16);
    }
  }
#pragma unroll
  for (int r = 0; r < 2; r++) {
    int rh = wn * 32 + r * 16 + (l & 15);
#pragma unroll
    for (int s = 0; s < 2; s++) {
      int ck = s * 4 + (l >> 4);
      offB[r][s] = rh * 128 + ((ck ^ (rh & 7)) * 16);
    }
  }

  // prologue: stage tiles 0,1; retire tile0 (leave tile1's 4 loads in flight)
  stageT(0, 0);
  stageT(1, 1);
  asm volatile("s_waitcnt vmcnt(4)" ::: "memory");
  __builtin_amdgcn_s_barrier();

  // per tile: stage(u+2) -> 12 ds_reads -> [compiler lgkm] -> 64 MFMA
  //           -> vmcnt(4) [retires stage(u+1)] -> barrier
#define GTILE(QB, SU, VMW)                                                        \
  {                                                                               \
    if ((SU) >= 0) stageT(((QB) + 2) % 3, (SU));                                  \
    const char* AP = shraw + (QB) * 32768;                                        \
    const char* BP = AP + 16384;                                                  \
    short8 a_[4][2], b_[2][2];                                                    \
    _Pragma("unroll") for (int j = 0; j < 4; j++) {                               \
      a_[j][0] = *(const short8*)(AP + offA[j][0]);                               \
      a_[j][1] = *(const short8*)(AP + offA[j][1]);                               \
    }                                                                             \
    _Pragma("unroll") for (int r = 0; r < 2; r++) {                               \
      b_[r][0] = *(const short8*)(BP + offB[r][0]);                               \
      b_[r][1] = *(const short8*)(BP + offB[r][1]);                               \
    }                                                                             \
    _Pragma("unroll") for (int j = 0; j < 4; j++)                                 \
      _Pragma("unroll") for (int r = 0; r < 2; r++) {                             \
        acc[j][r] = __builtin_amdgcn_mfma_f32_16x16x32_bf16(a_[j][0], b_[r][0],   \
                                                            acc[j][r], 0, 0, 0);  \
        acc[j][r] = __builtin_amdgcn_mfma_f32_16x16x32_bf16(a_[j][1], b_[r][1],   \
                                                            acc[j][r], 0, 0, 0);  \
      }                                                                           \
    asm volatile("s_waitcnt vmcnt(" VMW ")" ::: "memory");                        \
    __builtin_amdgcn_s_barrier();                                                 \
  }

  for (int base = 0; base < 27; base += 3) {
    GTILE(0, base + 2, "4")
    GTILE(1, base + 3, "4")
    GTILE(2, base + 4, "4")
  }
  GTILE(0, 29, "4")   // u=27
  GTILE(1, 30, "4")   // u=28
  GTILE(2, 31, "4")   // u=29
  GTILE(0, -1, "0")   // u=30: drain stage(31)
  GTILE(1, -1, "0")   // u=31

  // element (row_l, col_l): row_l = wm*64 + j*16 + (l>>4)*4 + v,
  //                         col_l = wn*32 + r*16 + (l&15)

  // ---- C^T pack + store -> mirror block [col0, row0] (covers diagonal too) ----
#pragma unroll
  for (int h = 0; h < 2; h++) {
    __syncthreads();
    unsigned short (*tileT)[TPC] = (unsigned short(*)[TPC])shraw;
    if (wm == h) {
#pragma unroll
      for (int j = 0; j < 4; j++) {
        int lr = j * 16 + (l >> 4) * 4;   // local orig-row within chunk (0..63)
#pragma unroll
        for (int r = 0; r < 2; r++) {
          int C = wn * 32 + r * 16 + (l & 15);
          ushort4v pk;
          pk[0] = f2h(acc[j][r][0]);
          pk[1] = f2h(acc[j][r][1]);
          pk[2] = f2h(acc[j][r][2]);
          pk[3] = f2h(acc[j][r][3]);
          *(ushort4v*)(&tileT[C][lr]) = pk;
        }
      }
    }
    __syncthreads();
    int c = tid >> 2, seg = tid & 3;     // 128 rows x 4 threads, 16 elems each
    const unsigned short* srcp = &tileT[c][seg * 16];
    unsigned short* dstp = sim + (size_t)(col0 + c) * NB + row0 + h * 64 + seg * 16;
    *(short8*)(dstp) = *(const short8*)(srcp);
    *(short8*)(dstp + 8) = *(const short8*)(srcp + 8);
  }

  // ---- direct pack + store -> own block [row0, col0] (off-diagonal only) ----
  if (bi != bj) {
#pragma unroll
    for (int h = 0; h < 2; h++) {
      __syncthreads();
      unsigned short (*tileR)[TPC] = (unsigned short(*)[TPC])shraw;
      if ((wn >> 1) == h) {
#pragma unroll
        for (int j = 0; j < 4; j++)
#pragma unroll
          for (int r = 0; r < 2; r++) {
            int row_l = wm * 64 + j * 16 + (l >> 4) * 4;
            int ch = (wn & 1) * 32 + r * 16 + (l & 15);   // col within chunk
#pragma unroll
            for (int v = 0; v < 4; v++)
              tileR[row_l + v][ch] = f2h(acc[j][r][v]);
          }
      }
      __syncthreads();
      int r_ = tid >> 2, seg = tid & 3;
      const unsigned short* srcp = &tileR[r_][seg * 16];
      unsigned short* dstp = sim + (size_t)(row0 + r_) * NB + col0 + h * 64 + seg * 16;
      *(short8*)(dstp) = *(const short8*)(srcp);
      *(short8*)(dstp + 8) = *(const short8*)(srcp + 8);
    }
  }
}

// ---- kernel 3: fused stats + exp-sums, FOUR waves per row (quarter-row each) ----
__global__ __launch_bounds__(512) void sums_kernel(const unsigned short* __restrict__ sim,
                                                   const int* __restrict__ labels,
                                                   float* __restrict__ gps,
                                                   float* __restrict__ gns) {
  int t = threadIdx.x, l = t & 63, w = t >> 6;   // 8 waves
  int rloc = w >> 2, quarter = w & 3;            // 2 rows/block, 4 waves/row
  int r = blockIdx.x * 2 + rloc;
  int rl = labels[r];
  const unsigned short* row = sim + (size_t)r * NB + quarter * 1024;
  int jbase = quarter * 1024;

  short8 sv[2];
  float pmin = 3.0e38f, nmax = -3.0e38f;
#pragma unroll
  for (int it = 0; it < 2; it++) {
    int j0 = it * 512 + l * 8;
    sv[it] = *(const short8*)(row + j0);
    int4 lb0 = *(const int4*)(labels + jbase + j0);
    int4 lb1 = *(const int4*)(labels + jbase + j0 + 4);
    int lb[8] = {lb0.x, lb0.y, lb0.z, lb0.w, lb1.x, lb1.y, lb1.z, lb1.w};
#pragma unroll
    for (int e = 0; e < 8; e++) {
      float s = h2f((unsigned short)sv[it][e]);
      int j = jbase + j0 + e;
      if (lb[e] == rl) {
        if (j != r && s < 0.99999f) pmin = fminf(pmin, s);
      } else {
        nmax = fmaxf(nmax, s);
      }
    }
  }
#pragma unroll
  for (int off = 1; off < 64; off <<= 1) {
    pmin = fminf(pmin, __shfl_xor(pmin, off));
    nmax = fmaxf(nmax, __shfl_xor(nmax, off));
  }
  // combine the 4 quarter-row waves
  __shared__ float spm[8], snm[8], sps[8], sns[8];
  if (l == 0) { spm[w] = pmin; snm[w] = nmax; }
  __syncthreads();
  int g = w & ~3;
  pmin = fminf(fminf(spm[g], spm[g + 1]), fminf(spm[g + 2], spm[g + 3]));
  nmax = fmaxf(fmaxf(snm[g], snm[g + 1]), fmaxf(snm[g + 2], snm[g + 3]));
  // empty-mask semantics: sentinels keep masks false -> sums 0 -> invalid (matches ref)

  float ps0 = 0.f, ps1 = 0.f, ns0 = 0.f, ns1 = 0.f;
#pragma unroll
  for (int it = 0; it < 2; it++) {
    int j0 = it * 512 + l * 8;
    int4 lb0 = *(const int4*)(labels + jbase + j0);
    int4 lb1 = *(const int4*)(labels + jbase + j0 + 4);
    int lb[8] = {lb0.x, lb0.y, lb0.z, lb0.w, lb1.x, lb1.y, lb1.z, lb1.w};
#pragma unroll
    for (int e = 0; e < 8; e++) {
      float s = h2f((unsigned short)sv[it][e]);
      int j = jbase + j0 + e;
      float pv = 0.f, nv = 0.f;
      if (lb[e] == rl) {
        if (j != r && s < 0.99999f && (s - 0.1f < nmax)) pv = __expf(-2.0f * (s - 0.5f));
      } else {
        if (s + 0.1f > pmin) nv = __expf(40.0f * (s - 0.5f));
      }
      if (e & 1) { ps1 += pv; ns1 += nv; }
      else       { ps0 += pv; ns0 += nv; }
    }
  }
  float ps = ps0 + ps1, ns = ns0 + ns1;
  for (int off = 32; off > 0; off >>= 1) {
    ps += __shfl_down(ps, off);
    ns += __shfl_down(ns, off);
  }
  if (l == 0) { sps[w] = ps; sns[w] = ns; }
  __syncthreads();
  if (t < 2) {
    gps[blockIdx.x * 2 + t] = sps[4 * t] + sps[4 * t + 1] + sps[4 * t + 2] + sps[4 * t + 3];
    gns[blockIdx.x * 2 + t] = sns[4 * t] + sns[4 * t + 1] + sns[4 * t + 2] + sns[4 * t + 3];
  }
}

// ---- kernel 4: finalize scalar loss ----
__global__ __launch_bounds__(256) void finalize_kernel(const float* __restrict__ gps,
                                                       const float* __restrict__ gns,
                                                       float* __restrict__ out) {
  int t = threadIdx.x;
  float sum = 0.f;
  for (int i = t; i < NB; i += 256) {
    float ps = gps[i], ns = gns[i];
    if (ps > 0.f && ns > 0.f) sum += 0.5f * log1pf(ps) + 0.025f * log1pf(ns);
  }
  for (int off = 32; off > 0; off >>= 1) sum += __shfl_down(sum, off);
  __shared__ float wsum[4];
  int lane = t & 63, wid = t >> 6;
  if (lane == 0) wsum[wid] = sum;
  __syncthreads();
  if (t == 0) out[0] = (wsum[0] + wsum[1] + wsum[2] + wsum[3]) / (float)NB;
}

extern "C" void kernel_launch(void* const* d_in, const int* in_sizes, int n_in,
                              void* d_out, int out_size, void* d_ws, size_t ws_size,
                              hipStream_t stream) {
  const float* feats = (const float*)d_in[0];
  const int* labels = (const int*)d_in[1];

  char* ws = (char*)d_ws;
  unsigned short* fb = (unsigned short*)ws;                  // 16 MB bf16 normalized feats
  size_t off = (size_t)NB * ND * 2;
  unsigned short* sim = (unsigned short*)(ws + off);         // 32 MB fp16 sim (full)
  off += (size_t)NB * NB * 2;
  float* gps = (float*)(ws + off); off += NB * 4;
  float* gns = (float*)(ws + off); off += NB * 4;

  norm_kernel<<<NB, 256, 0, stream>>>(feats, fb);
  pass0_kernel<<<NBLK, 512, 0, stream>>>(fb, sim);
  sums_kernel<<<NB / 2, 512, 0, stream>>>(sim, labels, gps, gns);
  finalize_kernel<<<1, 256, 0, stream>>>(gps, gns, (float*)d_out);
}